// Round 1
// baseline (226.161 us; speedup 1.0000x reference)
//
#include <hip/hip_runtime.h>
#include <math.h>

// Problem constants (from reference): D=32, H=64, B=2, N=512, M=512
namespace {
constexpr int D_ = 32;
constexpr int H_ = 64;
constexpr int B_ = 2;
constexpr int N_ = 512;
constexpr int M_ = 512;
constexpr int NROWS = B_ * N_ + B_ * M_;   // 2048 rows total (Q rows then K rows)
constexpr int LSTR = 580;                  // packed-transposed matrix stride (576 payload + 4 pad; 580%32=4)
constexpr int TN = 12;                     // n-tile   (12x16 -> 28 matrices * 580 * 4B = 64,960 B LDS)
constexpr int TM = 16;                     // m-tile
}

// ---------------------------------------------------------------------------
// Phase 1a: h[r][j] = silu(x_r @ w1 + b1)[j] for all 2048 rows (Q rows then K)
// ---------------------------------------------------------------------------
__global__ __launch_bounds__(64) void k_hidden(
    const float* __restrict__ Q, const float* __restrict__ K,
    const float* __restrict__ w1, const float* __restrict__ b1,
    float* __restrict__ h)
{
    const int r = blockIdx.x;        // 0..2047
    const int j = threadIdx.x;       // 0..63
    const float* x = (r < B_ * N_) ? (Q + (size_t)r * D_)
                                   : (K + (size_t)(r - B_ * N_) * D_);
    float z = b1[j];
    #pragma unroll
    for (int i = 0; i < D_; ++i)
        z = fmaf(x[i], w1[i * H_ + j], z);
    h[r * H_ + j] = z / (1.0f + __expf(-z));   // silu
}

// ---------------------------------------------------------------------------
// Phase 1b: raw = h @ w2 + b2; clamp 5*tanh(raw/5); +I; tril; softplus diag.
// Tiled GEMM: block = 64 rows x 256 cols, K=64. Stores L row-major [2048][1024].
// ---------------------------------------------------------------------------
__global__ __launch_bounds__(256) void k_makeL(
    const float* __restrict__ h, const float* __restrict__ w2,
    const float* __restrict__ b2, float* __restrict__ L)
{
    __shared__ __attribute__((aligned(16))) float hs[64][H_ + 1];   // 16.6 KB (pad 65: 520%32=8 -> conflict-free)
    __shared__ __attribute__((aligned(16))) float w2s[32][256];     // 32 KB

    const int p0 = blockIdx.x * 256;   // 4 col tiles
    const int r0 = blockIdx.y * 64;    // 32 row tiles
    const int t  = threadIdx.x;
    const int tr = t >> 5;             // 0..7  (8 rows each)
    const int tp = t & 31;             // 0..31 (8 cols each, stride 32)

    for (int idx = t; idx < 64 * H_; idx += 256) {
        int r = idx >> 6, j = idx & 63;
        hs[r][j] = h[(r0 + r) * H_ + j];
    }

    float acc[8][8];
    #pragma unroll
    for (int u = 0; u < 8; ++u)
        #pragma unroll
        for (int v = 0; v < 8; ++v) acc[u][v] = 0.0f;

    for (int jc = 0; jc < H_; jc += 32) {
        __syncthreads();               // covers hs fill (1st iter) + w2s reuse
        #pragma unroll
        for (int rep = 0; rep < 8; ++rep) {
            int idx = t * 4 + rep * 1024;
            int jj = idx >> 8;
            int pp = idx & 255;
            *(float4*)&w2s[jj][pp] = *(const float4*)&w2[(jc + jj) * 1024 + p0 + pp];
        }
        __syncthreads();
        #pragma unroll
        for (int j = 0; j < 32; ++j) {
            float a[8], bv[8];
            #pragma unroll
            for (int u = 0; u < 8; ++u) a[u] = hs[tr * 8 + u][jc + j];
            #pragma unroll
            for (int v = 0; v < 8; ++v) bv[v] = w2s[j][v * 32 + tp];
            #pragma unroll
            for (int u = 0; u < 8; ++u)
                #pragma unroll
                for (int v = 0; v < 8; ++v)
                    acc[u][v] = fmaf(a[u], bv[v], acc[u][v]);
        }
    }

    // epilogue: clamp, add identity, tril mask, softplus diagonal
    #pragma unroll
    for (int u = 0; u < 8; ++u) {
        int r = r0 + tr * 8 + u;
        #pragma unroll
        for (int v = 0; v < 8; ++v) {
            int p = p0 + v * 32 + tp;
            float raw = acc[u][v] + b2[p];
            float c = 5.0f * tanhf(0.2f * raw);      // soft clamp
            int i = p >> 5, jcol = p & 31;
            float val;
            if (i < jcol) {
                val = 0.0f;                           // strict upper: zeroed by tril
            } else if (i == jcol) {
                float z = c + 1.0f;                   // +identity on diagonal
                val = log1pf(__expf(z)) + 1e-4f;      // softplus (z in [-4,6], no overflow)
            } else {
                val = c;
            }
            L[(size_t)r * 1024 + p] = val;
        }
    }
}

// ---------------------------------------------------------------------------
// Phase 2: out[b,n,m] = sqrt(clip(0.5*(||Lq^T d||^2 + ||Lk^T d||^2), 1e-6, 1e6))
// Tile 12n x 16m per block (192 thr, 1 pair/thread). L tiles staged in LDS as
// TRANSPOSED + triangular-packed rows padded to x4 so column-j reads are
// contiguous ds_read_b128. Row j holds L[i][j] for i in [4*(j/4), 32).
// off(4g) = 8g(17-g); row length 32-4g.
// ---------------------------------------------------------------------------
__global__ __launch_bounds__(192) void k_pair(
    const float* __restrict__ Q, const float* __restrict__ K,
    const float* __restrict__ L, float* __restrict__ out)
{
    __shared__ __attribute__((aligned(16))) float ltq[TN][LSTR];
    __shared__ __attribute__((aligned(16))) float ltk[TM][LSTR];

    const int mt = blockIdx.x;     // 0..31
    const int nt = blockIdx.y;     // 0..42   (43*12 = 516 >= 512, guarded)
    const int b  = blockIdx.z;     // 0..1
    const int n0 = nt * TN;
    const int m0 = mt * TM;
    const int t  = threadIdx.x;
    const int nl = t >> 4;         // 0..11
    const int ml = t & 15;         // 0..15

    // ---- stage + repack 28 L matrices (float4 global reads, scalar LDS scatter)
    for (int idx = t; idx < (TN + TM) * 256; idx += 192) {
        int mat = idx >> 8;              // matrix id 0..27
        int e4  = idx & 255;             // float4 index within matrix
        int i   = e4 >> 3;               // L row   0..31
        int j4  = (e4 & 7) << 2;         // L col chunk start (aligned 4)
        int g   = j4 >> 2;
        if (i < 4 * g) continue;         // entirely above stored band
        int row;
        float* base;
        if (mat < TN) {
            int n = n0 + mat;
            if (n >= N_) continue;       // OOB n-tile tail
            row = b * N_ + n;
            base = &ltq[mat][0];
        } else {
            row = B_ * N_ + b * M_ + (m0 + (mat - TN));
            base = &ltk[mat - TN][0];
        }
        float4 v = *(const float4*)&L[(size_t)row * 1024 + i * 32 + j4];
        int rowlen = 32 - 4 * g;
        int slot = 8 * g * (17 - g) + (i - 4 * g);
        base[slot]              = v.x;
        base[slot +     rowlen] = v.y;
        base[slot + 2 * rowlen] = v.z;
        base[slot + 3 * rowlen] = v.w;
    }
    __syncthreads();

    const int n = n0 + nl;
    if (n < N_) {
        const float* qrow = Q + ((size_t)b * N_ + n) * D_;
        const float* krow = K + ((size_t)b * M_ + m0 + ml) * D_;
        float4 dl[8];
        #pragma unroll
        for (int c = 0; c < 8; ++c) {
            float4 qa = *(const float4*)&qrow[c * 4];
            float4 ka = *(const float4*)&krow[c * 4];
            dl[c] = make_float4(qa.x - ka.x, qa.y - ka.y, qa.z - ka.z, qa.w - ka.w);
        }
        float accq = 0.0f, acck = 0.0f;
        int off = 0;
        #pragma unroll
        for (int g = 0; g < 8; ++g) {
            #pragma unroll
            for (int jj = 0; jj < 4; ++jj) {
                float sq = 0.0f, sk = 0.0f;
                #pragma unroll
                for (int c = g; c < 8; ++c) {
                    const float4 aq = *(const float4*)&ltq[nl][off + 4 * (c - g)];
                    const float4 ak = *(const float4*)&ltk[ml][off + 4 * (c - g)];
                    const float4 dd = dl[c];
                    sq += aq.x * dd.x + aq.y * dd.y + aq.z * dd.z + aq.w * dd.w;
                    sk += ak.x * dd.x + ak.y * dd.y + ak.z * dd.z + ak.w * dd.w;
                }
                accq += sq * sq;
                acck += sk * sk;
                off += 32 - 4 * g;
            }
        }
        float ds = 0.5f * (accq + acck);
        ds = fminf(fmaxf(ds, 1e-6f), 1e6f);
        out[((size_t)b * N_ + n) * M_ + (m0 + ml)] = sqrtf(ds);
    }
}

// ---------------------------------------------------------------------------
extern "C" void kernel_launch(void* const* d_in, const int* in_sizes, int n_in,
                              void* d_out, int out_size, void* d_ws, size_t ws_size,
                              hipStream_t stream)
{
    const float* Q  = (const float*)d_in[0];
    const float* K  = (const float*)d_in[1];
    const float* w1 = (const float*)d_in[2];
    const float* b1 = (const float*)d_in[3];
    const float* w2 = (const float*)d_in[4];
    const float* b2 = (const float*)d_in[5];
    float* out = (float*)d_out;

    float* h = (float*)d_ws;                       // [2048][64]   = 512 KB
    float* L = h + (size_t)NROWS * H_;             // [2048][1024] = 8 MB

    k_hidden<<<dim3(NROWS), dim3(64), 0, stream>>>(Q, K, w1, b1, h);
    k_makeL<<<dim3(1024 / 256, NROWS / 64), dim3(256), 0, stream>>>(h, w2, b2, L);
    k_pair<<<dim3(M_ / TM, (N_ + TN - 1) / TN, B_), dim3(TN * TM), 0, stream>>>(Q, K, L, out);
}

// Round 2
// 132.020 us; speedup vs baseline: 1.7131x; 1.7131x over previous
//
#include <hip/hip_runtime.h>
#include <math.h>

namespace {
constexpr int KF = 1152;    // padded feature dim (1120 used + 32 zeros)
}

typedef __bf16 v8bf __attribute__((ext_vector_type(8)));
typedef float  v4f  __attribute__((ext_vector_type(4)));

__device__ __forceinline__ unsigned short f2bf(float f) {
    union { float f; unsigned u; } v; v.f = f;
    unsigned r = v.u + 0x7FFFu + ((v.u >> 16) & 1u);
    return (unsigned short)(r >> 16);
}

// column-major triangular index: pr in [0,528) -> (i,j) with i>=j
// start(j) = j*(65-j)/2, pr = start(j) + (i-j)
__device__ __forceinline__ void tri_cm(int pr, int& i, int& j) {
    j = (int)((65.0f - sqrtf(4225.0f - 8.0f * (float)pr)) * 0.5f);
    while (j > 0 && j * (65 - j) / 2 > pr) --j;
    while ((j + 1) * (64 - j) / 2 <= pr) ++j;
    i = j + (pr - j * (65 - j) / 2);
}

// ---------------------------------------------------------------------------
// K1: per-row feature builder. 8 rows/block, 256 threads, grid 256.
// x -> h = silu(x@w1+b1) -> L (clamp/tril/softplus) -> G=L L^T -> u=Gx, c=x'Gx
// Emits bf16 feature rows: A (Q rows): [g2 | outer | u | x | 0]
//                          B (K rows): [outer | g2 | -2x | -2u | 0]
// and fp32 c per row.
// ---------------------------------------------------------------------------
__global__ __launch_bounds__(256) void k_feat(
    const float* __restrict__ Q, const float* __restrict__ K,
    const float* __restrict__ w1, const float* __restrict__ b1,
    const float* __restrict__ w2, const float* __restrict__ b2,
    unsigned short* __restrict__ featA, unsigned short* __restrict__ featB,
    float* __restrict__ cOut)
{
    __shared__ __attribute__((aligned(16))) float x_s[8][32];
    __shared__ __attribute__((aligned(16))) float h_s[8][64];
    __shared__ __attribute__((aligned(16))) float L_s[8][32][36]; // pad 36: float4-aligned rows
    __shared__ __attribute__((aligned(16))) float G_s[8][528];    // column-major packed
    __shared__ __attribute__((aligned(16))) float u_s[8][32];

    const int t  = threadIdx.x;
    const int g0 = blockIdx.x * 8;

    // ---- load x (8 rows x 32)
    {
        int r = t >> 5, i = t & 31;
        int g = g0 + r;
        const float* src = (g < 1024) ? (Q + (size_t)g * 32)
                                      : (K + (size_t)(g - 1024) * 32);
        x_s[r][i] = src[i];
    }
    __syncthreads();

    // ---- h = silu(x @ w1 + b1): 512 outputs, 2/thread
    #pragma unroll
    for (int rep = 0; rep < 2; ++rep) {
        int o = t + rep * 256;
        int r = o >> 6, j = o & 63;
        float z = b1[j];
        #pragma unroll
        for (int i = 0; i < 32; ++i) z = fmaf(x_s[r][i], w1[i * 64 + j], z);
        h_s[r][j] = z / (1.0f + __expf(-z));
    }
    __syncthreads();

    // ---- raw = h @ w2 + b2 -> L.  Thread t owns p-quad [4t,4t+4), all 8 rows.
    {
        const int p4 = t * 4;
        float acc[8][4];
        float4 bq = *(const float4*)&b2[p4];
        #pragma unroll
        for (int r = 0; r < 8; ++r) {
            acc[r][0] = bq.x; acc[r][1] = bq.y; acc[r][2] = bq.z; acc[r][3] = bq.w;
        }
        for (int jb = 0; jb < 8; ++jb) {
            float h8[8][8];
            #pragma unroll
            for (int r = 0; r < 8; ++r) {
                *(float4*)&h8[r][0] = *(const float4*)&h_s[r][jb * 8 + 0];
                *(float4*)&h8[r][4] = *(const float4*)&h_s[r][jb * 8 + 4];
            }
            #pragma unroll
            for (int jj = 0; jj < 8; ++jj) {
                float4 w = *(const float4*)&w2[(size_t)(jb * 8 + jj) * 1024 + p4];
                #pragma unroll
                for (int r = 0; r < 8; ++r) {
                    acc[r][0] = fmaf(h8[r][jj], w.x, acc[r][0]);
                    acc[r][1] = fmaf(h8[r][jj], w.y, acc[r][1]);
                    acc[r][2] = fmaf(h8[r][jj], w.z, acc[r][2]);
                    acc[r][3] = fmaf(h8[r][jj], w.w, acc[r][3]);
                }
            }
        }
        // epilogue: clamp 5*tanh(raw/5), +I, tril, softplus diag
        const int i  = p4 >> 5;
        const int j0 = p4 & 31;
        #pragma unroll
        for (int r = 0; r < 8; ++r) {
            float4 lv;
            float* lvp = (float*)&lv;
            #pragma unroll
            for (int e = 0; e < 4; ++e) {
                int j = j0 + e;
                float raw = acc[r][e];
                float ex = __expf(0.4f * raw);
                float c5 = 5.0f * (ex - 1.0f) / (ex + 1.0f);
                float val;
                if (i < j)       val = 0.0f;
                else if (i == j) { float z = c5 + 1.0f; val = log1pf(__expf(z)) + 1e-4f; }
                else             val = c5;
                lvp[e] = val;
            }
            *(float4*)&L_s[r][i][j0] = lv;
        }
    }
    __syncthreads();

    // ---- G = L L^T (lower triangle, column-major packed for lane uniformity)
    for (int idx = t; idx < 8 * 528; idx += 256) {
        int r  = idx / 528;
        int pr = idx - r * 528;
        int i, j;
        tri_cm(pr, i, j);
        const float* Li = &L_s[r][i][0];
        const float* Lj = &L_s[r][j][0];
        float s = 0.0f;
        int nf = (j + 1) >> 2;
        for (int q = 0; q < nf; ++q) {
            float4 a  = *(const float4*)&Li[q * 4];
            float4 bb = *(const float4*)&Lj[q * 4];
            s += a.x * bb.x + a.y * bb.y + a.z * bb.z + a.w * bb.w;
        }
        for (int tt = nf * 4; tt <= j; ++tt) s = fmaf(Li[tt], Lj[tt], s);
        G_s[r][pr] = s;
    }
    __syncthreads();

    // ---- u = G x (symmetric lookup)
    {
        int r = t >> 5, i = t & 31;
        float s = 0.0f;
        #pragma unroll
        for (int j = 0; j < 32; ++j) {
            float gv = (j <= i) ? G_s[r][j * (65 - j) / 2 + i - j]
                                : G_s[r][i * (65 - i) / 2 + j - i];
            s = fmaf(gv, x_s[r][j], s);
        }
        u_s[r][i] = s;
    }
    __syncthreads();

    // ---- c = x' G x = u . x
    if (t < 8) {
        float s = 0.0f;
        #pragma unroll
        for (int i = 0; i < 32; ++i) s = fmaf(u_s[t][i], x_s[t][i], s);
        cOut[g0 + t] = s;
    }

    // ---- write bf16 feature rows
    for (int r = 0; r < 8; ++r) {
        int g = g0 + r;
        bool isA = (g < 1024);
        unsigned short* dst = isA ? (featA + (size_t)g * KF)
                                  : (featB + (size_t)(g - 1024) * KF);
        for (int pos = t; pos < KF; pos += 256) {
            float va;
            if (pos < 528) {
                int i, j; tri_cm(pos, i, j);
                float gv = G_s[r][pos] * ((i == j) ? 1.0f : 2.0f);
                float ov = x_s[r][i] * x_s[r][j];
                va = isA ? gv : ov;
            } else if (pos < 1056) {
                int pr = pos - 528;
                int i, j; tri_cm(pr, i, j);
                float gv = G_s[r][pr] * ((i == j) ? 1.0f : 2.0f);
                float ov = x_s[r][i] * x_s[r][j];
                va = isA ? ov : gv;
            } else if (pos < 1088) {
                int i = pos - 1056;
                va = isA ? u_s[r][i] : -2.0f * x_s[r][i];
            } else if (pos < 1120) {
                int i = pos - 1088;
                va = isA ? x_s[r][i] : -2.0f * u_s[r][i];
            } else {
                va = 0.0f;   // ws is poisoned 0xAA — must write the pad
            }
            dst[pos] = f2bf(va);
        }
    }
}

// ---------------------------------------------------------------------------
// K2: out[b,n,m] = sqrt(clip(0.5*(cA[n]+cB[m]+A_n.B_m))).  One wave per 32x32
// tile, K=1152 in 36 steps of 32, 2x2 grid of 16x16x32 bf16 MFMA.
// LDS tiles padded to 40 halves/row (80 B) for balanced bank quads.
// ---------------------------------------------------------------------------
__global__ __launch_bounds__(64) void k_gemm(
    const unsigned short* __restrict__ featA,
    const unsigned short* __restrict__ featB,
    const float* __restrict__ cOut,
    float* __restrict__ out)
{
    __shared__ __attribute__((aligned(16))) unsigned short As[32 * 40];
    __shared__ __attribute__((aligned(16))) unsigned short Bs[32 * 40];

    const int lane = threadIdx.x;
    const int m0 = blockIdx.x * 32;
    const int n0 = blockIdx.y * 32;
    const int b  = blockIdx.z;

    const unsigned short* Ap = featA + (size_t)(b * 512 + n0) * KF;
    const unsigned short* Bp = featB + (size_t)(b * 512 + m0) * KF;

    const int srow = lane >> 2;        // staging row 0..15
    const int sq   = lane & 3;         // 16B chunk within 32-half row
    const size_t goff0 = (size_t)srow * KF + sq * 8;
    const size_t goff1 = (size_t)(srow + 16) * KF + sq * 8;
    const int woff = srow * 40 + sq * 8;

    v4f acc00 = {0,0,0,0}, acc01 = {0,0,0,0}, acc10 = {0,0,0,0}, acc11 = {0,0,0,0};

    uint4 ra0 = *(const uint4*)(Ap + goff0);
    uint4 ra1 = *(const uint4*)(Ap + goff1);
    uint4 rb0 = *(const uint4*)(Bp + goff0);
    uint4 rb1 = *(const uint4*)(Bp + goff1);

    const int fr = lane & 15;          // fragment row/col
    const int fq = lane >> 4;          // k-quad
    const int ra = fr * 40 + fq * 8;

    for (int ks = 0; ks < 36; ++ks) {
        __syncthreads();
        *(uint4*)&As[woff]           = ra0;
        *(uint4*)&As[woff + 16 * 40] = ra1;
        *(uint4*)&Bs[woff]           = rb0;
        *(uint4*)&Bs[woff + 16 * 40] = rb1;
        if (ks + 1 < 36) {
            int k0 = (ks + 1) * 32;
            ra0 = *(const uint4*)(Ap + goff0 + k0);
            ra1 = *(const uint4*)(Ap + goff1 + k0);
            rb0 = *(const uint4*)(Bp + goff0 + k0);
            rb1 = *(const uint4*)(Bp + goff1 + k0);
        }
        __syncthreads();
        v8bf a0  = *(const v8bf*)&As[ra];
        v8bf a1  = *(const v8bf*)&As[ra + 16 * 40];
        v8bf b0v = *(const v8bf*)&Bs[ra];
        v8bf b1v = *(const v8bf*)&Bs[ra + 16 * 40];
        acc00 = __builtin_amdgcn_mfma_f32_16x16x32_bf16(a0, b0v, acc00, 0, 0, 0);
        acc01 = __builtin_amdgcn_mfma_f32_16x16x32_bf16(a0, b1v, acc01, 0, 0, 0);
        acc10 = __builtin_amdgcn_mfma_f32_16x16x32_bf16(a1, b0v, acc10, 0, 0, 0);
        acc11 = __builtin_amdgcn_mfma_f32_16x16x32_bf16(a1, b1v, acc11, 0, 0, 0);
    }

    // epilogue: D row = n (lane>>4)*4+v, col = m (lane&15)
    const int colm = lane & 15;
    const float cB_0 = cOut[1024 + b * 512 + m0 + colm];
    const float cB_1 = cOut[1024 + b * 512 + m0 + 16 + colm];
    const int rbase = lane >> 4;
    #pragma unroll
    for (int v = 0; v < 4; ++v) {
        int n_lo = n0 + rbase * 4 + v;
        int n_hi = n_lo + 16;
        float cA_lo = cOut[b * 512 + n_lo];
        float cA_hi = cOut[b * 512 + n_hi];
        float vv[4] = { acc00[v], acc01[v], acc10[v], acc11[v] };
        int   nn[4] = { n_lo, n_lo, n_hi, n_hi };
        int   mm[4] = { m0 + colm, m0 + 16 + colm, m0 + colm, m0 + 16 + colm };
        float cc[4] = { cA_lo + cB_0, cA_lo + cB_1, cA_hi + cB_0, cA_hi + cB_1 };
        #pragma unroll
        for (int e = 0; e < 4; ++e) {
            float dsq = 0.5f * (vv[e] + cc[e]);
            dsq = fminf(fmaxf(dsq, 1e-6f), 1e6f);
            out[((size_t)(b * 512 + nn[e])) * 512 + mm[e]] = sqrtf(dsq);
        }
    }
}

// ---------------------------------------------------------------------------
extern "C" void kernel_launch(void* const* d_in, const int* in_sizes, int n_in,
                              void* d_out, int out_size, void* d_ws, size_t ws_size,
                              hipStream_t stream)
{
    const float* Q  = (const float*)d_in[0];
    const float* K  = (const float*)d_in[1];
    const float* w1 = (const float*)d_in[2];
    const float* b1 = (const float*)d_in[3];
    const float* w2 = (const float*)d_in[4];
    const float* b2 = (const float*)d_in[5];
    float* out = (float*)d_out;

    unsigned short* featA = (unsigned short*)d_ws;            // [1024][1152] bf16
    unsigned short* featB = featA + (size_t)1024 * KF;        // [1024][1152] bf16
    float* cOut = (float*)(featB + (size_t)1024 * KF);        // [2048] fp32

    k_feat<<<dim3(256), dim3(256), 0, stream>>>(Q, K, w1, b1, w2, b2, featA, featB, cOut);
    k_gemm<<<dim3(16, 16, 2), dim3(64), 0, stream>>>(featA, featB, cOut, out);
}

// Round 3
// 102.788 us; speedup vs baseline: 2.2003x; 1.2844x over previous
//
#include <hip/hip_runtime.h>
#include <math.h>

namespace {
constexpr int KF  = 1152;   // padded feature dim (1120 used + 32 zeros)
constexpr int RPB = 4;      // rows per k_feat block
}

typedef __bf16 v8bf __attribute__((ext_vector_type(8)));
typedef float  v4f  __attribute__((ext_vector_type(4)));

__device__ __forceinline__ unsigned short f2bf(float f) {
    union { float f; unsigned u; } v; v.f = f;
    unsigned r = v.u + 0x7FFFu + ((v.u >> 16) & 1u);
    return (unsigned short)(r >> 16);
}

__device__ __forceinline__ v8bf as_v8bf(uint4 u) {
    union { uint4 u; v8bf b; } c; c.u = u; return c.b;
}

// ---------------------------------------------------------------------------
// K1: per-row feature builder. 4 rows/block, 256 threads, grid 512 (2 blk/CU).
// x -> h = silu(x@w1+b1) -> L (clamp/tril/softplus) -> G=L L^T -> u=Gx, c=x'Gx
// Features (bf16): A (Q rows): [G*2offdiag | outer(x) | u | x | 0pad]
//                  B (K rows): [outer(x) | G*2offdiag | -2x | -2u | 0pad]
// so that A_n . B_m = x_n'G_n x_m ... full bilinear expansion; c kept fp32.
// Triangular (i,j) decode via a 528-entry LDS table built once per block.
// ---------------------------------------------------------------------------
__global__ __launch_bounds__(256) void k_feat(
    const float* __restrict__ Q, const float* __restrict__ K,
    const float* __restrict__ w1, const float* __restrict__ b1,
    const float* __restrict__ w2, const float* __restrict__ b2,
    unsigned short* __restrict__ featA, unsigned short* __restrict__ featB,
    float* __restrict__ cOut)
{
    __shared__ __attribute__((aligned(16))) float x_s[RPB][32];
    __shared__ __attribute__((aligned(16))) float h_s[RPB][64];
    __shared__ __attribute__((aligned(16))) float L_s[RPB][32][36];
    __shared__ __attribute__((aligned(16))) float G_s[RPB][528];   // col-major packed
    __shared__ __attribute__((aligned(16))) float u_s[RPB][32];
    __shared__ unsigned short tri_s[528];                          // (i<<8)|j

    const int t  = threadIdx.x;
    const int g0 = blockIdx.x * RPB;

    // ---- triangular index table (once)
    for (int pr = t; pr < 528; pr += 256) {
        int j = (int)((65.0f - sqrtf(4225.0f - 8.0f * (float)pr)) * 0.5f);
        while (j > 0 && j * (65 - j) / 2 > pr) --j;
        while ((j + 1) * (64 - j) / 2 <= pr) ++j;
        int i = j + (pr - j * (65 - j) / 2);
        tri_s[pr] = (unsigned short)((i << 8) | j);
    }
    // ---- load x
    if (t < RPB * 32) {
        int r = t >> 5, i = t & 31;
        int g = g0 + r;
        const float* src = (g < 1024) ? (Q + (size_t)g * 32)
                                      : (K + (size_t)(g - 1024) * 32);
        x_s[r][i] = src[i];
    }
    __syncthreads();

    // ---- h = silu(x @ w1 + b1): 256 outputs, 1/thread
    {
        int r = t >> 6, j = t & 63;
        float z = b1[j];
        #pragma unroll
        for (int i = 0; i < 32; ++i) z = fmaf(x_s[r][i], w1[i * 64 + j], z);
        h_s[r][j] = z / (1.0f + __expf(-z));
    }
    __syncthreads();

    // ---- raw = h @ w2 + b2 -> L.  Thread t owns p-quad [4t,4t+4), all 4 rows.
    {
        const int p4 = t * 4;
        float acc[RPB][4];
        float4 bq = *(const float4*)&b2[p4];
        #pragma unroll
        for (int r = 0; r < RPB; ++r) {
            acc[r][0] = bq.x; acc[r][1] = bq.y; acc[r][2] = bq.z; acc[r][3] = bq.w;
        }
        for (int jb = 0; jb < 8; ++jb) {
            float h8[RPB][8];
            #pragma unroll
            for (int r = 0; r < RPB; ++r) {
                *(float4*)&h8[r][0] = *(const float4*)&h_s[r][jb * 8 + 0];
                *(float4*)&h8[r][4] = *(const float4*)&h_s[r][jb * 8 + 4];
            }
            #pragma unroll
            for (int jj = 0; jj < 8; ++jj) {
                float4 w = *(const float4*)&w2[(size_t)(jb * 8 + jj) * 1024 + p4];
                #pragma unroll
                for (int r = 0; r < RPB; ++r) {
                    acc[r][0] = fmaf(h8[r][jj], w.x, acc[r][0]);
                    acc[r][1] = fmaf(h8[r][jj], w.y, acc[r][1]);
                    acc[r][2] = fmaf(h8[r][jj], w.z, acc[r][2]);
                    acc[r][3] = fmaf(h8[r][jj], w.w, acc[r][3]);
                }
            }
        }
        const int i  = p4 >> 5;
        const int j0 = p4 & 31;
        #pragma unroll
        for (int r = 0; r < RPB; ++r) {
            float4 lv;
            float* lvp = (float*)&lv;
            #pragma unroll
            for (int e = 0; e < 4; ++e) {
                int j = j0 + e;
                float raw = acc[r][e];
                float ex = __expf(0.4f * raw);
                float c5 = 5.0f * (ex - 1.0f) / (ex + 1.0f);   // 5*tanh(raw/5)
                float val;
                if (i < j)       val = 0.0f;
                else if (i == j) { float z = c5 + 1.0f; val = log1pf(__expf(z)) + 1e-4f; }
                else             val = c5;
                lvp[e] = val;
            }
            *(float4*)&L_s[r][i][j0] = lv;
        }
    }
    __syncthreads();

    // ---- G = L L^T (lower triangle, packed column-major)
    for (int idx = t; idx < RPB * 528; idx += 256) {
        int r  = idx / 528;
        int pr = idx - r * 528;
        int tv = tri_s[pr];
        int i = tv >> 8, j = tv & 255;
        const float* Li = &L_s[r][i][0];
        const float* Lj = &L_s[r][j][0];
        float s = 0.0f;
        int nf = (j + 1) >> 2;
        for (int q = 0; q < nf; ++q) {
            float4 a  = *(const float4*)&Li[q * 4];
            float4 bb = *(const float4*)&Lj[q * 4];
            s += a.x * bb.x + a.y * bb.y + a.z * bb.z + a.w * bb.w;
        }
        for (int tt = nf * 4; tt <= j; ++tt) s = fmaf(Li[tt], Lj[tt], s);
        G_s[r][pr] = s;
    }
    __syncthreads();

    // ---- u = G x
    if (t < RPB * 32) {
        int r = t >> 5, i = t & 31;
        float s = 0.0f;
        #pragma unroll
        for (int j = 0; j < 32; ++j) {
            float gv = (j <= i) ? G_s[r][j * (65 - j) / 2 + i - j]
                                : G_s[r][i * (65 - i) / 2 + j - i];
            s = fmaf(gv, x_s[r][j], s);
        }
        u_s[r][i] = s;
    }
    __syncthreads();

    // ---- c = u . x
    if (t < RPB) {
        float s = 0.0f;
        #pragma unroll
        for (int i = 0; i < 32; ++i) s = fmaf(u_s[t][i], x_s[t][i], s);
        cOut[g0 + t] = s;
    }

    // ---- feature write: quads of 4 bf16, packed uint2 stores (coalesced).
    // All region boundaries (528/1056/1088/1120/1152) are multiples of 4.
    for (int idx = t; idx < RPB * (KF / 4); idx += 256) {
        int r   = idx / (KF / 4);
        int q   = idx - r * (KF / 4);
        int pos = q * 4;
        int g   = g0 + r;
        bool isA = (g < 1024);
        unsigned short* dst = isA ? (featA + (size_t)g * KF)
                                  : (featB + (size_t)(g - 1024) * KF);
        unsigned short ev[4];
        #pragma unroll
        for (int e = 0; e < 4; ++e) {
            int p = pos + e;
            float va;
            if (p < 1056) {
                int pr = (p < 528) ? p : p - 528;
                bool wantG = (p < 528) ? isA : !isA;
                int tv = tri_s[pr];
                int i = tv >> 8, j = tv & 255;
                float gv = G_s[r][pr] * ((i == j) ? 1.0f : 2.0f);
                float ov = x_s[r][i] * x_s[r][j];
                va = wantG ? gv : ov;
            } else if (p < 1088) {
                int i = p - 1056;
                va = isA ? u_s[r][i] : -2.0f * x_s[r][i];
            } else if (p < 1120) {
                int i = p - 1088;
                va = isA ? x_s[r][i] : -2.0f * u_s[r][i];
            } else {
                va = 0.0f;   // ws re-poisoned 0xAA — pad must be written
            }
            ev[e] = f2bf(va);
        }
        uint2 w;
        w.x = (unsigned)ev[0] | ((unsigned)ev[1] << 16);
        w.y = (unsigned)ev[2] | ((unsigned)ev[3] << 16);
        *(uint2*)(dst + pos) = w;
    }
}

// ---------------------------------------------------------------------------
// K2: out = sqrt(clip(0.5*(cA+cB+A.B))). One wave per 32x32 tile, NO LDS:
// MFMA fragments are row-contiguous 16B global reads; depth-3 register
// prefetch pipeline, no barriers.
// ---------------------------------------------------------------------------
__global__ __launch_bounds__(64) void k_gemm(
    const unsigned short* __restrict__ featA,
    const unsigned short* __restrict__ featB,
    const float* __restrict__ cOut,
    float* __restrict__ out)
{
    const int lane = threadIdx.x;
    const int m0 = blockIdx.x * 32;
    const int n0 = blockIdx.y * 32;
    const int b  = blockIdx.z;
    const int fr = lane & 15;
    const int fq = lane >> 4;

    const unsigned short* pA0 = featA + (size_t)(b * 512 + n0 + fr) * KF + fq * 8;
    const unsigned short* pA1 = pA0 + (size_t)16 * KF;
    const unsigned short* pB0 = featB + (size_t)(b * 512 + m0 + fr) * KF + fq * 8;
    const unsigned short* pB1 = pB0 + (size_t)16 * KF;

    v4f acc00 = {0,0,0,0}, acc01 = {0,0,0,0}, acc10 = {0,0,0,0}, acc11 = {0,0,0,0};

    uint4 bA0[3], bA1[3], bB0[3], bB1[3];
    #pragma unroll
    for (int s = 0; s < 3; ++s) {
        bA0[s] = *(const uint4*)(pA0 + s * 32);
        bA1[s] = *(const uint4*)(pA1 + s * 32);
        bB0[s] = *(const uint4*)(pB0 + s * 32);
        bB1[s] = *(const uint4*)(pB1 + s * 32);
    }

    for (int ks = 0; ks < 36; ks += 3) {
        #pragma unroll
        for (int s = 0; s < 3; ++s) {
            v8bf a0  = as_v8bf(bA0[s]);
            v8bf a1  = as_v8bf(bA1[s]);
            v8bf b0v = as_v8bf(bB0[s]);
            v8bf b1v = as_v8bf(bB1[s]);
            int kn = ks + s + 3;
            if (kn < 36) {
                bA0[s] = *(const uint4*)(pA0 + kn * 32);
                bA1[s] = *(const uint4*)(pA1 + kn * 32);
                bB0[s] = *(const uint4*)(pB0 + kn * 32);
                bB1[s] = *(const uint4*)(pB1 + kn * 32);
            }
            acc00 = __builtin_amdgcn_mfma_f32_16x16x32_bf16(a0, b0v, acc00, 0, 0, 0);
            acc01 = __builtin_amdgcn_mfma_f32_16x16x32_bf16(a0, b1v, acc01, 0, 0, 0);
            acc10 = __builtin_amdgcn_mfma_f32_16x16x32_bf16(a1, b0v, acc10, 0, 0, 0);
            acc11 = __builtin_amdgcn_mfma_f32_16x16x32_bf16(a1, b1v, acc11, 0, 0, 0);
        }
    }

    // epilogue: D row = n (lane>>4)*4+v, col = m (lane&15)
    const int colm = lane & 15;
    const float cB_0 = cOut[1024 + b * 512 + m0 + colm];
    const float cB_1 = cOut[1024 + b * 512 + m0 + 16 + colm];
    const int rbase = lane >> 4;
    #pragma unroll
    for (int v = 0; v < 4; ++v) {
        int n_lo = n0 + rbase * 4 + v;
        int n_hi = n_lo + 16;
        float cA_lo = cOut[b * 512 + n_lo];
        float cA_hi = cOut[b * 512 + n_hi];
        float vv[4] = { acc00[v], acc01[v], acc10[v], acc11[v] };
        int   nn[4] = { n_lo, n_lo, n_hi, n_hi };
        int   mm[4] = { m0 + colm, m0 + 16 + colm, m0 + colm, m0 + 16 + colm };
        float cc[4] = { cA_lo + cB_0, cA_lo + cB_1, cA_hi + cB_0, cA_hi + cB_1 };
        #pragma unroll
        for (int e = 0; e < 4; ++e) {
            float dsq = 0.5f * (vv[e] + cc[e]);
            dsq = fminf(fmaxf(dsq, 1e-6f), 1e6f);
            out[((size_t)(b * 512 + nn[e])) * 512 + mm[e]] = sqrtf(dsq);
        }
    }
}

// ---------------------------------------------------------------------------
extern "C" void kernel_launch(void* const* d_in, const int* in_sizes, int n_in,
                              void* d_out, int out_size, void* d_ws, size_t ws_size,
                              hipStream_t stream)
{
    const float* Q  = (const float*)d_in[0];
    const float* K  = (const float*)d_in[1];
    const float* w1 = (const float*)d_in[2];
    const float* b1 = (const float*)d_in[3];
    const float* w2 = (const float*)d_in[4];
    const float* b2 = (const float*)d_in[5];
    float* out = (float*)d_out;

    unsigned short* featA = (unsigned short*)d_ws;            // [1024][1152] bf16
    unsigned short* featB = featA + (size_t)1024 * KF;        // [1024][1152] bf16
    float* cOut = (float*)(featB + (size_t)1024 * KF);        // [2048] fp32

    k_feat<<<dim3(2048 / RPB), dim3(256), 0, stream>>>(Q, K, w1, b1, w2, b2, featA, featB, cOut);
    k_gemm<<<dim3(16, 16, 2), dim3(64), 0, stream>>>(featA, featB, cOut, out);
}